// Round 1
// baseline (274.413 us; speedup 1.0000x reference)
//
#include <hip/hip_runtime.h>
#include <stdint.h>

// All I/O fp32. MFMA bf16 path, weights as A-operand (A[m=out][k]), activations
// as B (B[k][n=point]). Layer->layer D->B handoff is in-lane only because each
// next layer's weights are pre-permuted along input dim:
//   P(k) = 4*(k>>3) + (k&3) + 16*((k>>2)&1)
// R4: all weight frags staged to LDS per block (compiler couldn't keep 160
// VGPR of weights resident -> was re-loading from global each iter = latency
// bound, MfmaUtil 6.5%). Two independent 16-point groups interleaved per
// iteration for ILP + weight-read amortization. Biases resident in VGPR.
// R5: occupancy fix. Counters showed latency-bound (Occ 15.9%, VALUBusy 27%,
// MfmaUtil 6.8%, HBM 25%) at 512 blocks = 2 blocks/CU. LDS 40KB and VGPR 128
// both allow exactly 4 blocks/CU -> IT 4->2, grid 512->1024 (exactly 4/CU,
// no tail), __launch_bounds__(256,4). Extra ws staging reads are L2-resident.

typedef __attribute__((ext_vector_type(8))) __bf16 bf16x8;
typedef __attribute__((ext_vector_type(4))) float f32x4;

union FragU { uint32_t u[4]; bf16x8 v; uint4 q; };

__device__ __forceinline__ unsigned short f2bf(float f) {
    union { float f; uint32_t i; } v; v.f = f;
    return (unsigned short)((v.i + 0x7FFFu + ((v.i >> 16) & 1u)) >> 16); // RTNE
}
__device__ __forceinline__ float bf2f(uint32_t u16) {
    union { uint32_t i; float f; } v; v.i = u16 << 16; return v.f;
}
__device__ __forceinline__ uint32_t pk2(float x, float y) {
    return (uint32_t)f2bf(x) | ((uint32_t)f2bf(y) << 16);
}
__device__ __forceinline__ int permK(int k) {
    return 4 * (k >> 3) + (k & 3) + 16 * ((k >> 2) & 1);
}
__device__ __forceinline__ f32x4 MF(bf16x8 a, bf16x8 b, f32x4 c) {
    return __builtin_amdgcn_mfma_f32_16x16x32_bf16(a, b, c, 0, 0, 0);
}

// ws dword layout (10240 dwords):
//   [0,1024)    layer0 A-frags  [chunk(2)][tile(2)][lane(64)][dw(4)]  (K=60 pad 64)
//   [1024,3072) layers1-4 A     [L(4)][tile(2)][lane][dw]             (perm k)
//   [3072,3328) layer5 A        [lane][dw]                            (perm k, m>=8 zero)
//   [3328,7424) bank A          [k(8)][tile(2)][lane][dw]
//   [7424,9984) bias L0-4 fp32  [L(5)][tile(2)][lane][r(4)]
//   [9984,10240) bias L5 fp32   [lane][r]                             (m>=8 zero)

struct WPf { const float* p[13]; };

__global__ void pc_prep(WPf wp, uint32_t* __restrict__ ws) {
    int idx = blockIdx.x * blockDim.x + threadIdx.x;
    if (idx >= 10240) return;
    if (idx < 7424) {
        int layer, t, chunk = 0, lane, d; const float* w; bool perm;
        int r = idx;
        if (r < 1024) { chunk = r >> 9; r &= 511; t = r >> 8; r &= 255; lane = r >> 2; d = r & 3;
                        layer = 0; w = wp.p[0]; perm = false; }
        else if (r < 3072) { r -= 1024; layer = 1 + (r >> 9); r &= 511; t = r >> 8; r &= 255;
                             lane = r >> 2; d = r & 3; w = wp.p[2 * layer]; perm = true; }
        else if (r < 3328) { r -= 3072; layer = 5; t = 0; lane = r >> 2; d = r & 3;
                             w = wp.p[10]; perm = true; }
        else { r -= 3328; int bk = r >> 9; r &= 511; t = r >> 8; r &= 255; lane = r >> 2; d = r & 3;
               layer = -1; w = wp.p[12] + bk * 1024; perm = false; }
        int gq = lane >> 4, m = t * 16 + (lane & 15);
        uint32_t o = 0;
        #pragma unroll
        for (int e = 0; e < 2; ++e) {
            int kf = 8 * gq + 2 * d + e;
            float v = 0.f;
            if (layer == -1) {
                v = w[kf * 32 + m];                       // bank: A[m=o][k=i] = bank[k][i*32+o]
            } else {
                int ks = perm ? permK(kf) : (chunk * 32 + kf);
                if (layer == 0)      { if (ks < 60) v = w[ks * 32 + m]; }
                else if (layer == 5) { if (m < 8)   v = w[ks * 8 + m]; }
                else                 v = w[ks * 32 + m];  // A[m][k] = W[P(k)][m]
            }
            o |= ((uint32_t)f2bf(v)) << (16 * e);
        }
        ws[idx] = o;
    } else if (idx < 9984) {
        int r = idx - 7424; int L = r >> 9; r &= 511; int t = r >> 8; r &= 255;
        int lane = r >> 2, rr = r & 3;
        ((float*)ws)[idx] = wp.p[2 * L + 1][t * 16 + 4 * (lane >> 4) + rr];
    } else {
        int r = idx - 9984; int lane = r >> 2, rr = r & 3;
        int m = 4 * (lane >> 4) + rr;
        ((float*)ws)[idx] = (m < 8) ? wp.p[11][m] : 0.f;
    }
}

#define IT 2   // 32 points/iter * 2 iters = 64 points per wave; 4096 waves (4 blocks/CU)

__global__ __launch_bounds__(256, 4) void pc_main(
    const float* __restrict__ rel, const float* __restrict__ feat,
    const uint32_t* __restrict__ wsu, float* __restrict__ out)
{
    __shared__ __align__(16) uint32_t W[10240];   // 40 KB -> exactly 4 blocks/CU
    { // cooperative stage of all frags/biases: 2560 x uint4
        uint4* s4 = (uint4*)W;
        const uint4* g4 = (const uint4*)wsu;
        #pragma unroll
        for (int i = 0; i < 10; ++i) s4[threadIdx.x + 256 * i] = g4[threadIdx.x + 256 * i];
    }
    __syncthreads();

    const int lane = threadIdx.x & 63;
    const int wv = threadIdx.x >> 6;
    const int g = lane >> 4;
    const int n16 = lane & 15;

    // resident biases (C-operands)
    f32x4 Bi[5][2], Bi5;
    #pragma unroll
    for (int L = 0; L < 5; ++L)
        #pragma unroll
        for (int t = 0; t < 2; ++t) {
            float4 b = ((const float4*)(W + 7424 + L * 512 + t * 256))[lane];
            Bi[L][t][0] = b.x; Bi[L][t][1] = b.y; Bi[L][t][2] = b.z; Bi[L][t][3] = b.w;
        }
    {
        float4 b = ((const float4*)(W + 9984))[lane];
        Bi5[0] = b.x; Bi5[1] = b.y; Bi5[2] = b.z; Bi5[3] = b.w;
    }

    const size_t pt0 = (size_t)(blockIdx.x * 4 + wv) * (32 * IT);

    #define LDF(off) ({ FragU _f; _f.q = ((const uint4*)(W + (off)))[lane]; _f.v; })

    for (int it = 0; it < IT; ++it) {
        const size_t nA = pt0 + (size_t)it * 32 + n16;   // group 0 point; group 1 = +16

        // ---- layer0 B-frags (K=60, tail pad) for both groups ----
        FragU c0[2], c1[2];
        #pragma unroll
        for (int q = 0; q < 2; ++q) {
            const float* rrow = rel + (nA + 16 * q) * 60;
            float4 ra = *(const float4*)(rrow + 8 * g);
            float4 rb = *(const float4*)(rrow + 8 * g + 4);
            float4 rc = *(const float4*)(rrow + 32 + 8 * g);
            float4 rd = make_float4(0.f, 0.f, 0.f, 0.f);
            if (g < 3) rd = *(const float4*)(rrow + 36 + 8 * g);
            c0[q].u[0] = pk2(ra.x, ra.y); c0[q].u[1] = pk2(ra.z, ra.w);
            c0[q].u[2] = pk2(rb.x, rb.y); c0[q].u[3] = pk2(rb.z, rb.w);
            c1[q].u[0] = pk2(rc.x, rc.y); c1[q].u[1] = pk2(rc.z, rc.w);
            c1[q].u[2] = pk2(rd.x, rd.y); c1[q].u[3] = pk2(rd.z, rd.w);
        }

        f32x4 t0[2], t1[2];
        #pragma unroll
        for (int q = 0; q < 2; ++q) { t0[q] = Bi[0][0]; t1[q] = Bi[0][1]; }
        {
            bf16x8 w00 = LDF(0), w01 = LDF(256), w10 = LDF(512), w11 = LDF(768);
            #pragma unroll
            for (int q = 0; q < 2; ++q) {
                t0[q] = MF(w00, c0[q].v, t0[q]); t1[q] = MF(w01, c0[q].v, t1[q]);
                t0[q] = MF(w10, c1[q].v, t0[q]); t1[q] = MF(w11, c1[q].v, t1[q]);
            }
        }

        // ---- layers 1..4: leaky -> in-lane pack -> mfma (perm weights) ----
        #pragma unroll
        for (int L = 0; L < 4; ++L) {
            bf16x8 wa = LDF(1024 + L * 512), wb = LDF(1024 + L * 512 + 256);
            #pragma unroll
            for (int q = 0; q < 2; ++q) {
                FragU bx;
                #pragma unroll
                for (int r = 0; r < 4; ++r) {
                    t0[q][r] = fmaxf(t0[q][r], 0.01f * t0[q][r]);
                    t1[q][r] = fmaxf(t1[q][r], 0.01f * t1[q][r]);
                }
                bx.u[0] = pk2(t0[q][0], t0[q][1]); bx.u[1] = pk2(t0[q][2], t0[q][3]);
                bx.u[2] = pk2(t1[q][0], t1[q][1]); bx.u[3] = pk2(t1[q][2], t1[q][3]);
                t0[q] = MF(wa, bx.v, Bi[L + 1][0]);
                t1[q] = MF(wb, bx.v, Bi[L + 1][1]);
            }
        }

        // ---- layer5 (32->8) ----
        {
            bf16x8 w5 = LDF(3072);
            #pragma unroll
            for (int q = 0; q < 2; ++q) {
                FragU bx;
                #pragma unroll
                for (int r = 0; r < 4; ++r) {
                    t0[q][r] = fmaxf(t0[q][r], 0.01f * t0[q][r]);
                    t1[q][r] = fmaxf(t1[q][r], 0.01f * t1[q][r]);
                }
                bx.u[0] = pk2(t0[q][0], t0[q][1]); bx.u[1] = pk2(t0[q][2], t0[q][3]);
                bx.u[2] = pk2(t1[q][0], t1[q][1]); bx.u[3] = pk2(t1[q][2], t1[q][3]);
                t0[q] = MF(w5, bx.v, Bi5);   // logits m0..3 in g=0, m4..7 in g=1
            }
        }

        // ---- softmax over 8 per point, broadcast coeffs to all 4 g-groups ----
        float cw[2][8];
        #pragma unroll
        for (int q = 0; q < 2; ++q) {
            float m4 = fmaxf(fmaxf(t0[q][0], t0[q][1]), fmaxf(t0[q][2], t0[q][3]));
            float m8 = fmaxf(m4, __shfl_xor(m4, 16, 64));
            float e0 = __expf(t0[q][0] - m8), e1 = __expf(t0[q][1] - m8);
            float e2 = __expf(t0[q][2] - m8), e3 = __expf(t0[q][3] - m8);
            float s4 = e0 + e1 + e2 + e3;
            float s8 = s4 + __shfl_xor(s4, 16, 64);
            float inv = 1.0f / s8;
            uint32_t p01 = pk2(e0 * inv, e1 * inv);
            uint32_t p23 = pk2(e2 * inv, e3 * inv);
            uint32_t q01 = (uint32_t)__builtin_amdgcn_ds_bpermute(n16 * 4, (int)p01);
            uint32_t q23 = (uint32_t)__builtin_amdgcn_ds_bpermute(n16 * 4, (int)p23);
            uint32_t q45 = (uint32_t)__builtin_amdgcn_ds_bpermute((n16 + 16) * 4, (int)p01);
            uint32_t q67 = (uint32_t)__builtin_amdgcn_ds_bpermute((n16 + 16) * 4, (int)p23);
            cw[q][0] = bf2f(q01 & 0xffff); cw[q][1] = bf2f(q01 >> 16);
            cw[q][2] = bf2f(q23 & 0xffff); cw[q][3] = bf2f(q23 >> 16);
            cw[q][4] = bf2f(q45 & 0xffff); cw[q][5] = bf2f(q45 >> 16);
            cw[q][6] = bf2f(q67 & 0xffff); cw[q][7] = bf2f(q67 >> 16);
        }

        // ---- bank stage: out = sum_k c_k * (Bank_k . feat) ----
        FragU bf_[2];
        #pragma unroll
        for (int q = 0; q < 2; ++q) {
            const float* frow = feat + (nA + 16 * q) * 32 + 8 * g;
            float4 fa = *(const float4*)frow;
            float4 fb = *(const float4*)(frow + 4);
            bf_[q].u[0] = pk2(fa.x, fa.y); bf_[q].u[1] = pk2(fa.z, fa.w);
            bf_[q].u[2] = pk2(fb.x, fb.y); bf_[q].u[3] = pk2(fb.z, fb.w);
        }
        f32x4 o0[2], o1[2];
        #pragma unroll
        for (int q = 0; q < 2; ++q) {
            o0[q] = (f32x4){0.f, 0.f, 0.f, 0.f};
            o1[q] = (f32x4){0.f, 0.f, 0.f, 0.f};
        }
        #pragma unroll
        for (int k = 0; k < 8; ++k) {
            bf16x8 wk0 = LDF(3328 + k * 512), wk1 = LDF(3328 + k * 512 + 256);
            #pragma unroll
            for (int q = 0; q < 2; ++q) {
                f32x4 z = {0.f, 0.f, 0.f, 0.f};
                f32x4 u0 = MF(wk0, bf_[q].v, z);
                f32x4 u1 = MF(wk1, bf_[q].v, z);
                #pragma unroll
                for (int r = 0; r < 4; ++r) {
                    o0[q][r] += cw[q][k] * u0[r];
                    o1[q][r] += cw[q][k] * u1[r];
                }
            }
        }

        #pragma unroll
        for (int q = 0; q < 2; ++q) {
            float* orow = out + (nA + 16 * q) * 32;
            *(float4*)(orow + 4 * g)      = make_float4(o0[q][0], o0[q][1], o0[q][2], o0[q][3]);
            *(float4*)(orow + 16 + 4 * g) = make_float4(o1[q][0], o1[q][1], o1[q][2], o1[q][3]);
        }
    }
    #undef LDF
}

extern "C" void kernel_launch(void* const* d_in, const int* in_sizes, int n_in,
                              void* d_out, int out_size, void* d_ws, size_t ws_size,
                              hipStream_t stream)
{
    const float* rel = (const float*)d_in[0];
    const float* feat = (const float*)d_in[1];
    WPf wp;
    for (int i = 0; i < 13; ++i) wp.p[i] = (const float*)d_in[2 + i];
    uint32_t* ws = (uint32_t*)d_ws;
    float* out = (float*)d_out;

    const int npts = in_sizes[0] / 60;                 // 262144
    const int nblocks = npts / (32 * IT * 4);          // 1024 -> exactly 4 blocks/CU

    hipLaunchKernelGGL(pc_prep, dim3(40), dim3(256), 0, stream, wp, ws);
    hipLaunchKernelGGL(pc_main, dim3(nblocks), dim3(256), 0, stream, rel, feat, ws, out);
}

// Round 2
// 159.806 us; speedup vs baseline: 1.7172x; 1.7172x over previous
//
#include <hip/hip_runtime.h>
#include <stdint.h>

// All I/O fp32. MFMA bf16 path, weights as A-operand (A[m=out][k]), activations
// as B (B[k][n=point]). Layer->layer D->B handoff is in-lane only because each
// next layer's weights are pre-permuted along input dim:
//   P(k) = 4*(k>>3) + (k&3) + 16*((k>>2)&1)
// R4: all weight frags staged to LDS per block (compiler couldn't keep 160
// VGPR of weights resident -> was re-loading from global each iter = latency
// bound, MfmaUtil 6.5%). Two independent 16-point groups interleaved per
// iteration for ILP + weight-read amortization. Biases resident in VGPR.
// R5 (FAILED): __launch_bounds__(256,4) strangled the allocator -> 64 arch
// VGPRs -> massive scratch spill (FETCH 293MB, WRITE 205MB), 4x slower.
// Occupancy DID rise 16->36% as predicted, so the residency theory holds.
// R6: keep IT=2 / grid=1024 (4 blocks/CU of work, zero tail) but revert the
// bound to (256,2). Compiler's natural allocation is 128 VGPR / no spill,
// and 128 VGPR + 40KB LDS already permit 4 blocks/CU in hardware.

typedef __attribute__((ext_vector_type(8))) __bf16 bf16x8;
typedef __attribute__((ext_vector_type(4))) float f32x4;

union FragU { uint32_t u[4]; bf16x8 v; uint4 q; };

__device__ __forceinline__ unsigned short f2bf(float f) {
    union { float f; uint32_t i; } v; v.f = f;
    return (unsigned short)((v.i + 0x7FFFu + ((v.i >> 16) & 1u)) >> 16); // RTNE
}
__device__ __forceinline__ float bf2f(uint32_t u16) {
    union { uint32_t i; float f; } v; v.i = u16 << 16; return v.f;
}
__device__ __forceinline__ uint32_t pk2(float x, float y) {
    return (uint32_t)f2bf(x) | ((uint32_t)f2bf(y) << 16);
}
__device__ __forceinline__ int permK(int k) {
    return 4 * (k >> 3) + (k & 3) + 16 * ((k >> 2) & 1);
}
__device__ __forceinline__ f32x4 MF(bf16x8 a, bf16x8 b, f32x4 c) {
    return __builtin_amdgcn_mfma_f32_16x16x32_bf16(a, b, c, 0, 0, 0);
}

// ws dword layout (10240 dwords):
//   [0,1024)    layer0 A-frags  [chunk(2)][tile(2)][lane(64)][dw(4)]  (K=60 pad 64)
//   [1024,3072) layers1-4 A     [L(4)][tile(2)][lane][dw]             (perm k)
//   [3072,3328) layer5 A        [lane][dw]                            (perm k, m>=8 zero)
//   [3328,7424) bank A          [k(8)][tile(2)][lane][dw]
//   [7424,9984) bias L0-4 fp32  [L(5)][tile(2)][lane][r(4)]
//   [9984,10240) bias L5 fp32   [lane][r]                             (m>=8 zero)

struct WPf { const float* p[13]; };

__global__ void pc_prep(WPf wp, uint32_t* __restrict__ ws) {
    int idx = blockIdx.x * blockDim.x + threadIdx.x;
    if (idx >= 10240) return;
    if (idx < 7424) {
        int layer, t, chunk = 0, lane, d; const float* w; bool perm;
        int r = idx;
        if (r < 1024) { chunk = r >> 9; r &= 511; t = r >> 8; r &= 255; lane = r >> 2; d = r & 3;
                        layer = 0; w = wp.p[0]; perm = false; }
        else if (r < 3072) { r -= 1024; layer = 1 + (r >> 9); r &= 511; t = r >> 8; r &= 255;
                             lane = r >> 2; d = r & 3; w = wp.p[2 * layer]; perm = true; }
        else if (r < 3328) { r -= 3072; layer = 5; t = 0; lane = r >> 2; d = r & 3;
                             w = wp.p[10]; perm = true; }
        else { r -= 3328; int bk = r >> 9; r &= 511; t = r >> 8; r &= 255; lane = r >> 2; d = r & 3;
               layer = -1; w = wp.p[12] + bk * 1024; perm = false; }
        int gq = lane >> 4, m = t * 16 + (lane & 15);
        uint32_t o = 0;
        #pragma unroll
        for (int e = 0; e < 2; ++e) {
            int kf = 8 * gq + 2 * d + e;
            float v = 0.f;
            if (layer == -1) {
                v = w[kf * 32 + m];                       // bank: A[m=o][k=i] = bank[k][i*32+o]
            } else {
                int ks = perm ? permK(kf) : (chunk * 32 + kf);
                if (layer == 0)      { if (ks < 60) v = w[ks * 32 + m]; }
                else if (layer == 5) { if (m < 8)   v = w[ks * 8 + m]; }
                else                 v = w[ks * 32 + m];  // A[m][k] = W[P(k)][m]
            }
            o |= ((uint32_t)f2bf(v)) << (16 * e);
        }
        ws[idx] = o;
    } else if (idx < 9984) {
        int r = idx - 7424; int L = r >> 9; r &= 511; int t = r >> 8; r &= 255;
        int lane = r >> 2, rr = r & 3;
        ((float*)ws)[idx] = wp.p[2 * L + 1][t * 16 + 4 * (lane >> 4) + rr];
    } else {
        int r = idx - 9984; int lane = r >> 2, rr = r & 3;
        int m = 4 * (lane >> 4) + rr;
        ((float*)ws)[idx] = (m < 8) ? wp.p[11][m] : 0.f;
    }
}

#define IT 2   // 32 points/iter * 2 iters = 64 points per wave; 4096 waves (4 blocks/CU)

__global__ __launch_bounds__(256, 2) void pc_main(
    const float* __restrict__ rel, const float* __restrict__ feat,
    const uint32_t* __restrict__ wsu, float* __restrict__ out)
{
    __shared__ __align__(16) uint32_t W[10240];   // 40 KB -> up to 4 blocks/CU
    { // cooperative stage of all frags/biases: 2560 x uint4
        uint4* s4 = (uint4*)W;
        const uint4* g4 = (const uint4*)wsu;
        #pragma unroll
        for (int i = 0; i < 10; ++i) s4[threadIdx.x + 256 * i] = g4[threadIdx.x + 256 * i];
    }
    __syncthreads();

    const int lane = threadIdx.x & 63;
    const int wv = threadIdx.x >> 6;
    const int g = lane >> 4;
    const int n16 = lane & 15;

    // resident biases (C-operands)
    f32x4 Bi[5][2], Bi5;
    #pragma unroll
    for (int L = 0; L < 5; ++L)
        #pragma unroll
        for (int t = 0; t < 2; ++t) {
            float4 b = ((const float4*)(W + 7424 + L * 512 + t * 256))[lane];
            Bi[L][t][0] = b.x; Bi[L][t][1] = b.y; Bi[L][t][2] = b.z; Bi[L][t][3] = b.w;
        }
    {
        float4 b = ((const float4*)(W + 9984))[lane];
        Bi5[0] = b.x; Bi5[1] = b.y; Bi5[2] = b.z; Bi5[3] = b.w;
    }

    const size_t pt0 = (size_t)(blockIdx.x * 4 + wv) * (32 * IT);

    #define LDF(off) ({ FragU _f; _f.q = ((const uint4*)(W + (off)))[lane]; _f.v; })

    for (int it = 0; it < IT; ++it) {
        const size_t nA = pt0 + (size_t)it * 32 + n16;   // group 0 point; group 1 = +16

        // ---- layer0 B-frags (K=60, tail pad) for both groups ----
        FragU c0[2], c1[2];
        #pragma unroll
        for (int q = 0; q < 2; ++q) {
            const float* rrow = rel + (nA + 16 * q) * 60;
            float4 ra = *(const float4*)(rrow + 8 * g);
            float4 rb = *(const float4*)(rrow + 8 * g + 4);
            float4 rc = *(const float4*)(rrow + 32 + 8 * g);
            float4 rd = make_float4(0.f, 0.f, 0.f, 0.f);
            if (g < 3) rd = *(const float4*)(rrow + 36 + 8 * g);
            c0[q].u[0] = pk2(ra.x, ra.y); c0[q].u[1] = pk2(ra.z, ra.w);
            c0[q].u[2] = pk2(rb.x, rb.y); c0[q].u[3] = pk2(rb.z, rb.w);
            c1[q].u[0] = pk2(rc.x, rc.y); c1[q].u[1] = pk2(rc.z, rc.w);
            c1[q].u[2] = pk2(rd.x, rd.y); c1[q].u[3] = pk2(rd.z, rd.w);
        }

        f32x4 t0[2], t1[2];
        #pragma unroll
        for (int q = 0; q < 2; ++q) { t0[q] = Bi[0][0]; t1[q] = Bi[0][1]; }
        {
            bf16x8 w00 = LDF(0), w01 = LDF(256), w10 = LDF(512), w11 = LDF(768);
            #pragma unroll
            for (int q = 0; q < 2; ++q) {
                t0[q] = MF(w00, c0[q].v, t0[q]); t1[q] = MF(w01, c0[q].v, t1[q]);
                t0[q] = MF(w10, c1[q].v, t0[q]); t1[q] = MF(w11, c1[q].v, t1[q]);
            }
        }

        // ---- layers 1..4: leaky -> in-lane pack -> mfma (perm weights) ----
        #pragma unroll
        for (int L = 0; L < 4; ++L) {
            bf16x8 wa = LDF(1024 + L * 512), wb = LDF(1024 + L * 512 + 256);
            #pragma unroll
            for (int q = 0; q < 2; ++q) {
                FragU bx;
                #pragma unroll
                for (int r = 0; r < 4; ++r) {
                    t0[q][r] = fmaxf(t0[q][r], 0.01f * t0[q][r]);
                    t1[q][r] = fmaxf(t1[q][r], 0.01f * t1[q][r]);
                }
                bx.u[0] = pk2(t0[q][0], t0[q][1]); bx.u[1] = pk2(t0[q][2], t0[q][3]);
                bx.u[2] = pk2(t1[q][0], t1[q][1]); bx.u[3] = pk2(t1[q][2], t1[q][3]);
                t0[q] = MF(wa, bx.v, Bi[L + 1][0]);
                t1[q] = MF(wb, bx.v, Bi[L + 1][1]);
            }
        }

        // ---- layer5 (32->8) ----
        {
            bf16x8 w5 = LDF(3072);
            #pragma unroll
            for (int q = 0; q < 2; ++q) {
                FragU bx;
                #pragma unroll
                for (int r = 0; r < 4; ++r) {
                    t0[q][r] = fmaxf(t0[q][r], 0.01f * t0[q][r]);
                    t1[q][r] = fmaxf(t1[q][r], 0.01f * t1[q][r]);
                }
                bx.u[0] = pk2(t0[q][0], t0[q][1]); bx.u[1] = pk2(t0[q][2], t0[q][3]);
                bx.u[2] = pk2(t1[q][0], t1[q][1]); bx.u[3] = pk2(t1[q][2], t1[q][3]);
                t0[q] = MF(w5, bx.v, Bi5);   // logits m0..3 in g=0, m4..7 in g=1
            }
        }

        // ---- softmax over 8 per point, broadcast coeffs to all 4 g-groups ----
        float cw[2][8];
        #pragma unroll
        for (int q = 0; q < 2; ++q) {
            float m4 = fmaxf(fmaxf(t0[q][0], t0[q][1]), fmaxf(t0[q][2], t0[q][3]));
            float m8 = fmaxf(m4, __shfl_xor(m4, 16, 64));
            float e0 = __expf(t0[q][0] - m8), e1 = __expf(t0[q][1] - m8);
            float e2 = __expf(t0[q][2] - m8), e3 = __expf(t0[q][3] - m8);
            float s4 = e0 + e1 + e2 + e3;
            float s8 = s4 + __shfl_xor(s4, 16, 64);
            float inv = 1.0f / s8;
            uint32_t p01 = pk2(e0 * inv, e1 * inv);
            uint32_t p23 = pk2(e2 * inv, e3 * inv);
            uint32_t q01 = (uint32_t)__builtin_amdgcn_ds_bpermute(n16 * 4, (int)p01);
            uint32_t q23 = (uint32_t)__builtin_amdgcn_ds_bpermute(n16 * 4, (int)p23);
            uint32_t q45 = (uint32_t)__builtin_amdgcn_ds_bpermute((n16 + 16) * 4, (int)p01);
            uint32_t q67 = (uint32_t)__builtin_amdgcn_ds_bpermute((n16 + 16) * 4, (int)p23);
            cw[q][0] = bf2f(q01 & 0xffff); cw[q][1] = bf2f(q01 >> 16);
            cw[q][2] = bf2f(q23 & 0xffff); cw[q][3] = bf2f(q23 >> 16);
            cw[q][4] = bf2f(q45 & 0xffff); cw[q][5] = bf2f(q45 >> 16);
            cw[q][6] = bf2f(q67 & 0xffff); cw[q][7] = bf2f(q67 >> 16);
        }

        // ---- bank stage: out = sum_k c_k * (Bank_k . feat) ----
        FragU bf_[2];
        #pragma unroll
        for (int q = 0; q < 2; ++q) {
            const float* frow = feat + (nA + 16 * q) * 32 + 8 * g;
            float4 fa = *(const float4*)frow;
            float4 fb = *(const float4*)(frow + 4);
            bf_[q].u[0] = pk2(fa.x, fa.y); bf_[q].u[1] = pk2(fa.z, fa.w);
            bf_[q].u[2] = pk2(fb.x, fb.y); bf_[q].u[3] = pk2(fb.z, fb.w);
        }
        f32x4 o0[2], o1[2];
        #pragma unroll
        for (int q = 0; q < 2; ++q) {
            o0[q] = (f32x4){0.f, 0.f, 0.f, 0.f};
            o1[q] = (f32x4){0.f, 0.f, 0.f, 0.f};
        }
        #pragma unroll
        for (int k = 0; k < 8; ++k) {
            bf16x8 wk0 = LDF(3328 + k * 512), wk1 = LDF(3328 + k * 512 + 256);
            #pragma unroll
            for (int q = 0; q < 2; ++q) {
                f32x4 z = {0.f, 0.f, 0.f, 0.f};
                f32x4 u0 = MF(wk0, bf_[q].v, z);
                f32x4 u1 = MF(wk1, bf_[q].v, z);
                #pragma unroll
                for (int r = 0; r < 4; ++r) {
                    o0[q][r] += cw[q][k] * u0[r];
                    o1[q][r] += cw[q][k] * u1[r];
                }
            }
        }

        #pragma unroll
        for (int q = 0; q < 2; ++q) {
            float* orow = out + (nA + 16 * q) * 32;
            *(float4*)(orow + 4 * g)      = make_float4(o0[q][0], o0[q][1], o0[q][2], o0[q][3]);
            *(float4*)(orow + 16 + 4 * g) = make_float4(o1[q][0], o1[q][1], o1[q][2], o1[q][3]);
        }
    }
    #undef LDF
}

extern "C" void kernel_launch(void* const* d_in, const int* in_sizes, int n_in,
                              void* d_out, int out_size, void* d_ws, size_t ws_size,
                              hipStream_t stream)
{
    const float* rel = (const float*)d_in[0];
    const float* feat = (const float*)d_in[1];
    WPf wp;
    for (int i = 0; i < 13; ++i) wp.p[i] = (const float*)d_in[2 + i];
    uint32_t* ws = (uint32_t*)d_ws;
    float* out = (float*)d_out;

    const int npts = in_sizes[0] / 60;                 // 262144
    const int nblocks = npts / (32 * IT * 4);          // 1024 -> 4 blocks/CU of work

    hipLaunchKernelGGL(pc_prep, dim3(40), dim3(256), 0, stream, wp, ws);
    hipLaunchKernelGGL(pc_main, dim3(nblocks), dim3(256), 0, stream, rel, feat, ws, out);
}

// Round 3
// 158.007 us; speedup vs baseline: 1.7367x; 1.0114x over previous
//
#include <hip/hip_runtime.h>
#include <stdint.h>

// All I/O fp32. MFMA bf16 path, weights as A-operand (A[m=out][k]), activations
// as B (B[k][n=point]). Layer->layer D->B handoff is in-lane only because each
// next layer's weights are pre-permuted along input dim:
//   P(k) = 4*(k>>3) + (k&3) + 16*((k>>2)&1)
// R4: all weight frags staged to LDS per block. Two independent 16-point
// groups (q) interleaved per iteration for ILP. Biases resident in VGPR.
// R5 (FAILED): __launch_bounds__(256,4) -> 64 arch VGPR -> massive spill.
// R6: bounds back to (256,2), grid 1024: dur identical to R4 (41us, Occ 15%).
//   Conclusion: residency capped at 2 waves/SIMD by TOTAL unified reg use
//   (~256 incl acc regs; CSV's VGPR_Count=128 is arch-only). Grid never
//   mattered.
// R7: cut VALU + inter-layer critical path. Manual RTNE f2bf bit-twiddle
// (~9 VALU ops per packed pair, ~610 ops/iter, 40 packs ON the layer->layer
// serial chain) replaced by compiler-native (__bf16) casts which lower to
// v_cvt_pk_bf16_f32 (1 op/pair, RTNE, same numerics). Per m240: let the
// compiler emit it from casts; don't hand-write inline asm.

typedef __attribute__((ext_vector_type(8))) __bf16 bf16x8;
typedef __attribute__((ext_vector_type(2))) __bf16 bf16x2;
typedef __attribute__((ext_vector_type(4))) float f32x4;

union FragU { uint32_t u[4]; bf16x8 v; uint4 q; };

__device__ __forceinline__ unsigned short f2bf(float f) {
    union { float f; uint32_t i; } v; v.f = f;
    return (unsigned short)((v.i + 0x7FFFu + ((v.i >> 16) & 1u)) >> 16); // RTNE (prep only)
}
__device__ __forceinline__ float bf2f(uint32_t u16) {
    union { uint32_t i; float f; } v; v.i = u16 << 16; return v.f;
}
// native pack: compiler lowers the pair of casts to v_cvt_pk_bf16_f32 (RTNE)
__device__ __forceinline__ uint32_t pk2(float x, float y) {
    union { bf16x2 h; uint32_t u; } c;
    c.h[0] = (__bf16)x; c.h[1] = (__bf16)y;
    return c.u;
}
__device__ __forceinline__ bf16x8 pack8(float a, float b, float c, float d,
                                        float e, float f, float g, float h) {
    bf16x8 v;
    v[0] = (__bf16)a; v[1] = (__bf16)b; v[2] = (__bf16)c; v[3] = (__bf16)d;
    v[4] = (__bf16)e; v[5] = (__bf16)f; v[6] = (__bf16)g; v[7] = (__bf16)h;
    return v;
}
__device__ __forceinline__ int permK(int k) {
    return 4 * (k >> 3) + (k & 3) + 16 * ((k >> 2) & 1);
}
__device__ __forceinline__ f32x4 MF(bf16x8 a, bf16x8 b, f32x4 c) {
    return __builtin_amdgcn_mfma_f32_16x16x32_bf16(a, b, c, 0, 0, 0);
}

// ws dword layout (10240 dwords):
//   [0,1024)    layer0 A-frags  [chunk(2)][tile(2)][lane(64)][dw(4)]  (K=60 pad 64)
//   [1024,3072) layers1-4 A     [L(4)][tile(2)][lane][dw]             (perm k)
//   [3072,3328) layer5 A        [lane][dw]                            (perm k, m>=8 zero)
//   [3328,7424) bank A          [k(8)][tile(2)][lane][dw]
//   [7424,9984) bias L0-4 fp32  [L(5)][tile(2)][lane][r(4)]
//   [9984,10240) bias L5 fp32   [lane][r]                             (m>=8 zero)

struct WPf { const float* p[13]; };

__global__ void pc_prep(WPf wp, uint32_t* __restrict__ ws) {
    int idx = blockIdx.x * blockDim.x + threadIdx.x;
    if (idx >= 10240) return;
    if (idx < 7424) {
        int layer, t, chunk = 0, lane, d; const float* w; bool perm;
        int r = idx;
        if (r < 1024) { chunk = r >> 9; r &= 511; t = r >> 8; r &= 255; lane = r >> 2; d = r & 3;
                        layer = 0; w = wp.p[0]; perm = false; }
        else if (r < 3072) { r -= 1024; layer = 1 + (r >> 9); r &= 511; t = r >> 8; r &= 255;
                             lane = r >> 2; d = r & 3; w = wp.p[2 * layer]; perm = true; }
        else if (r < 3328) { r -= 3072; layer = 5; t = 0; lane = r >> 2; d = r & 3;
                             w = wp.p[10]; perm = true; }
        else { r -= 3328; int bk = r >> 9; r &= 511; t = r >> 8; r &= 255; lane = r >> 2; d = r & 3;
               layer = -1; w = wp.p[12] + bk * 1024; perm = false; }
        int gq = lane >> 4, m = t * 16 + (lane & 15);
        uint32_t o = 0;
        #pragma unroll
        for (int e = 0; e < 2; ++e) {
            int kf = 8 * gq + 2 * d + e;
            float v = 0.f;
            if (layer == -1) {
                v = w[kf * 32 + m];                       // bank: A[m=o][k=i] = bank[k][i*32+o]
            } else {
                int ks = perm ? permK(kf) : (chunk * 32 + kf);
                if (layer == 0)      { if (ks < 60) v = w[ks * 32 + m]; }
                else if (layer == 5) { if (m < 8)   v = w[ks * 8 + m]; }
                else                 v = w[ks * 32 + m];  // A[m][k] = W[P(k)][m]
            }
            o |= ((uint32_t)f2bf(v)) << (16 * e);
        }
        ws[idx] = o;
    } else if (idx < 9984) {
        int r = idx - 7424; int L = r >> 9; r &= 511; int t = r >> 8; r &= 255;
        int lane = r >> 2, rr = r & 3;
        ((float*)ws)[idx] = wp.p[2 * L + 1][t * 16 + 4 * (lane >> 4) + rr];
    } else {
        int r = idx - 9984; int lane = r >> 2, rr = r & 3;
        int m = 4 * (lane >> 4) + rr;
        ((float*)ws)[idx] = (m < 8) ? wp.p[11][m] : 0.f;
    }
}

#define IT 2   // 32 points/iter * 2 iters = 64 points per wave; 4096 waves

__global__ __launch_bounds__(256, 2) void pc_main(
    const float* __restrict__ rel, const float* __restrict__ feat,
    const uint32_t* __restrict__ wsu, float* __restrict__ out)
{
    __shared__ __align__(16) uint32_t W[10240];   // 40 KB
    { // cooperative stage of all frags/biases: 2560 x uint4
        uint4* s4 = (uint4*)W;
        const uint4* g4 = (const uint4*)wsu;
        #pragma unroll
        for (int i = 0; i < 10; ++i) s4[threadIdx.x + 256 * i] = g4[threadIdx.x + 256 * i];
    }
    __syncthreads();

    const int lane = threadIdx.x & 63;
    const int wv = threadIdx.x >> 6;
    const int g = lane >> 4;
    const int n16 = lane & 15;

    // resident biases (C-operands)
    f32x4 Bi[5][2], Bi5;
    #pragma unroll
    for (int L = 0; L < 5; ++L)
        #pragma unroll
        for (int t = 0; t < 2; ++t) {
            float4 b = ((const float4*)(W + 7424 + L * 512 + t * 256))[lane];
            Bi[L][t][0] = b.x; Bi[L][t][1] = b.y; Bi[L][t][2] = b.z; Bi[L][t][3] = b.w;
        }
    {
        float4 b = ((const float4*)(W + 9984))[lane];
        Bi5[0] = b.x; Bi5[1] = b.y; Bi5[2] = b.z; Bi5[3] = b.w;
    }

    const size_t pt0 = (size_t)(blockIdx.x * 4 + wv) * (32 * IT);

    #define LDF(off) ({ FragU _f; _f.q = ((const uint4*)(W + (off)))[lane]; _f.v; })

    for (int it = 0; it < IT; ++it) {
        const size_t nA = pt0 + (size_t)it * 32 + n16;   // group 0 point; group 1 = +16

        // ---- layer0 B-frags (K=60, tail pad) for both groups ----
        bf16x8 c0[2], c1[2];
        #pragma unroll
        for (int q = 0; q < 2; ++q) {
            const float* rrow = rel + (nA + 16 * q) * 60;
            float4 ra = *(const float4*)(rrow + 8 * g);
            float4 rb = *(const float4*)(rrow + 8 * g + 4);
            float4 rc = *(const float4*)(rrow + 32 + 8 * g);
            float4 rd = make_float4(0.f, 0.f, 0.f, 0.f);
            if (g < 3) rd = *(const float4*)(rrow + 36 + 8 * g);
            c0[q] = pack8(ra.x, ra.y, ra.z, ra.w, rb.x, rb.y, rb.z, rb.w);
            c1[q] = pack8(rc.x, rc.y, rc.z, rc.w, rd.x, rd.y, rd.z, rd.w);
        }

        f32x4 t0[2], t1[2];
        #pragma unroll
        for (int q = 0; q < 2; ++q) { t0[q] = Bi[0][0]; t1[q] = Bi[0][1]; }
        {
            bf16x8 w00 = LDF(0), w01 = LDF(256), w10 = LDF(512), w11 = LDF(768);
            #pragma unroll
            for (int q = 0; q < 2; ++q) {
                t0[q] = MF(w00, c0[q], t0[q]); t1[q] = MF(w01, c0[q], t1[q]);
                t0[q] = MF(w10, c1[q], t0[q]); t1[q] = MF(w11, c1[q], t1[q]);
            }
        }

        // ---- layers 1..4: leaky -> in-lane pack -> mfma (perm weights) ----
        #pragma unroll
        for (int L = 0; L < 4; ++L) {
            bf16x8 wa = LDF(1024 + L * 512), wb = LDF(1024 + L * 512 + 256);
            #pragma unroll
            for (int q = 0; q < 2; ++q) {
                #pragma unroll
                for (int r = 0; r < 4; ++r) {
                    t0[q][r] = fmaxf(t0[q][r], 0.01f * t0[q][r]);
                    t1[q][r] = fmaxf(t1[q][r], 0.01f * t1[q][r]);
                }
                bf16x8 bx = pack8(t0[q][0], t0[q][1], t0[q][2], t0[q][3],
                                  t1[q][0], t1[q][1], t1[q][2], t1[q][3]);
                t0[q] = MF(wa, bx, Bi[L + 1][0]);
                t1[q] = MF(wb, bx, Bi[L + 1][1]);
            }
        }

        // ---- layer5 (32->8) ----
        {
            bf16x8 w5 = LDF(3072);
            #pragma unroll
            for (int q = 0; q < 2; ++q) {
                #pragma unroll
                for (int r = 0; r < 4; ++r) {
                    t0[q][r] = fmaxf(t0[q][r], 0.01f * t0[q][r]);
                    t1[q][r] = fmaxf(t1[q][r], 0.01f * t1[q][r]);
                }
                bf16x8 bx = pack8(t0[q][0], t0[q][1], t0[q][2], t0[q][3],
                                  t1[q][0], t1[q][1], t1[q][2], t1[q][3]);
                t0[q] = MF(w5, bx, Bi5);   // logits m0..3 in g=0, m4..7 in g=1
            }
        }

        // ---- softmax over 8 per point, broadcast coeffs to all 4 g-groups ----
        float cw[2][8];
        #pragma unroll
        for (int q = 0; q < 2; ++q) {
            float m4 = fmaxf(fmaxf(t0[q][0], t0[q][1]), fmaxf(t0[q][2], t0[q][3]));
            float m8 = fmaxf(m4, __shfl_xor(m4, 16, 64));
            float e0 = __expf(t0[q][0] - m8), e1 = __expf(t0[q][1] - m8);
            float e2 = __expf(t0[q][2] - m8), e3 = __expf(t0[q][3] - m8);
            float s4 = e0 + e1 + e2 + e3;
            float s8 = s4 + __shfl_xor(s4, 16, 64);
            float inv = 1.0f / s8;
            uint32_t p01 = pk2(e0 * inv, e1 * inv);
            uint32_t p23 = pk2(e2 * inv, e3 * inv);
            uint32_t q01 = (uint32_t)__builtin_amdgcn_ds_bpermute(n16 * 4, (int)p01);
            uint32_t q23 = (uint32_t)__builtin_amdgcn_ds_bpermute(n16 * 4, (int)p23);
            uint32_t q45 = (uint32_t)__builtin_amdgcn_ds_bpermute((n16 + 16) * 4, (int)p01);
            uint32_t q67 = (uint32_t)__builtin_amdgcn_ds_bpermute((n16 + 16) * 4, (int)p23);
            cw[q][0] = bf2f(q01 & 0xffff); cw[q][1] = bf2f(q01 >> 16);
            cw[q][2] = bf2f(q23 & 0xffff); cw[q][3] = bf2f(q23 >> 16);
            cw[q][4] = bf2f(q45 & 0xffff); cw[q][5] = bf2f(q45 >> 16);
            cw[q][6] = bf2f(q67 & 0xffff); cw[q][7] = bf2f(q67 >> 16);
        }

        // ---- bank stage: out = sum_k c_k * (Bank_k . feat) ----
        bf16x8 bf_[2];
        #pragma unroll
        for (int q = 0; q < 2; ++q) {
            const float* frow = feat + (nA + 16 * q) * 32 + 8 * g;
            float4 fa = *(const float4*)frow;
            float4 fb = *(const float4*)(frow + 4);
            bf_[q] = pack8(fa.x, fa.y, fa.z, fa.w, fb.x, fb.y, fb.z, fb.w);
        }
        f32x4 o0[2], o1[2];
        #pragma unroll
        for (int q = 0; q < 2; ++q) {
            o0[q] = (f32x4){0.f, 0.f, 0.f, 0.f};
            o1[q] = (f32x4){0.f, 0.f, 0.f, 0.f};
        }
        #pragma unroll
        for (int k = 0; k < 8; ++k) {
            bf16x8 wk0 = LDF(3328 + k * 512), wk1 = LDF(3328 + k * 512 + 256);
            #pragma unroll
            for (int q = 0; q < 2; ++q) {
                f32x4 z = {0.f, 0.f, 0.f, 0.f};
                f32x4 u0 = MF(wk0, bf_[q], z);
                f32x4 u1 = MF(wk1, bf_[q], z);
                #pragma unroll
                for (int r = 0; r < 4; ++r) {
                    o0[q][r] += cw[q][k] * u0[r];
                    o1[q][r] += cw[q][k] * u1[r];
                }
            }
        }

        #pragma unroll
        for (int q = 0; q < 2; ++q) {
            float* orow = out + (nA + 16 * q) * 32;
            *(float4*)(orow + 4 * g)      = make_float4(o0[q][0], o0[q][1], o0[q][2], o0[q][3]);
            *(float4*)(orow + 16 + 4 * g) = make_float4(o1[q][0], o1[q][1], o1[q][2], o1[q][3]);
        }
    }
    #undef LDF
}

extern "C" void kernel_launch(void* const* d_in, const int* in_sizes, int n_in,
                              void* d_out, int out_size, void* d_ws, size_t ws_size,
                              hipStream_t stream)
{
    const float* rel = (const float*)d_in[0];
    const float* feat = (const float*)d_in[1];
    WPf wp;
    for (int i = 0; i < 13; ++i) wp.p[i] = (const float*)d_in[2 + i];
    uint32_t* ws = (uint32_t*)d_ws;
    float* out = (float*)d_out;

    const int npts = in_sizes[0] / 60;                 // 262144
    const int nblocks = npts / (32 * IT * 4);          // 1024

    hipLaunchKernelGGL(pc_prep, dim3(40), dim3(256), 0, stream, wp, ws);
    hipLaunchKernelGGL(pc_main, dim3(nblocks), dim3(256), 0, stream, rel, feat, ws, out);
}